// Round 1
// baseline (434.021 us; speedup 1.0000x reference)
//
#include <hip/hip_runtime.h>
#include <stdint.h>

#define NUM_TOKENS 16384
#define DIM        4096
#define NEXP       256
#define MB         32      // tokens per block
#define BK         64      // K per staging step
#define NITER      (DIM / BK)
#define APAD       72      // A row stride (+8 kills bank conflicts, keeps 16B align)
#define NWAVES     8
#define MARGIN     0.025f  // ~8.6 sigma of the pure-bf16 gap error (std ~2.9e-3)
#define CAP        16384   // refinement list capacity

typedef __attribute__((ext_vector_type(4))) float   f32x4;
typedef __attribute__((ext_vector_type(8))) __bf16  bf16x8;

static __device__ __forceinline__ unsigned short f32_to_bf16(float f) {
    unsigned int u = __float_as_uint(f);
    u += 0x7fffu + ((u >> 16) & 1u);     // round-to-nearest-even
    return (unsigned short)(u >> 16);
}

// ---------------------------------------------------------------- kernel 1
// Convert weight fp32 -> bf16; zero the refinement counter.
__global__ void cvt_weights(const float* __restrict__ w,
                            unsigned short* __restrict__ wh,
                            int* __restrict__ counter) {
    if (blockIdx.x == 0 && threadIdx.x == 0) *counter = 0;
    const int n4 = NEXP * DIM / 4;
    const int stride = gridDim.x * blockDim.x;
    for (int i = blockIdx.x * blockDim.x + threadIdx.x; i < n4; i += stride) {
        float4 v = ((const float4*)w)[i];
        ushort4 h;
        h.x = f32_to_bf16(v.x); h.y = f32_to_bf16(v.y);
        h.z = f32_to_bf16(v.z); h.w = f32_to_bf16(v.w);
        ((ushort4*)wh)[i] = h;
    }
}

// ---------------------------------------------------------------- kernel 2
// Fused bf16 GEMM + top-2: block = 32 tokens x 256 experts, full K.
// 512 thr / 8 waves; wave = 32 tokens x 32 experts (mt=2, nt=2).
//
// R6 change (this round): 2-deep pipelined LDS double-buffer with raw
// s_barrier + COUNTED vmcnt (T3/T4-lite). The old __syncthreads() forced
// vmcnt(0) every K-step, exposing the B-DMA L2 latency (~300cy) and the
// x HBM prefetch (~900cy) on every one of the 64 iterations — that, not
// BW or MFMA, is the theory for 430us vs the ~40us rooflines.
// Per-wave vmem queue entering iter it: [B(it)x4, x(it+1)]; after issuing
// B(it+1)x4 it is 9 deep -> s_waitcnt vmcnt(5) retires exactly B(it)
// while keeping B(it+1)+x(it+2) in flight across the barrier.
// LDS: 2x32K (B) + 2x4.5K (A) + 4K (cand) = 77.5 KB -> still 2 blocks/CU.
__global__ __launch_bounds__(512, 4) void gate_main(
    const float* __restrict__ x,
    const unsigned short* __restrict__ wh,
    float* __restrict__ out,           // [0,T) weights, [T,2T) indices (as float)
    int* __restrict__ counter,
    int4* __restrict__ entries)
{
    __shared__ unsigned short lAh[2][MB][APAD];    // 2 x 4.5 KB
    __shared__ unsigned short lBh[2][NEXP * BK];   // 2 x 32 KB
    __shared__ float4 cand[NWAVES][MB];            // 4 KB

    const int tid  = threadIdx.x;
    const int wv   = tid >> 6;          // wave 0..7 -> experts [wv*32, wv*32+32)
    const int lane = tid & 63;
    const int tok0 = blockIdx.x * MB;

    // A staging: thread covers token ta, 4 floats at kcol
    const int ta   = tid >> 4;          // 0..31
    const int kcol = (tid & 15) * 4;    // 0..60
    const float* xrow = x + (size_t)(tok0 + ta) * DIM + kcol;

    // B staging coords (XOR-swizzled source chunk): lane l writes LDS chunk
    // (l&7) of expert base+(l>>3); slot holds global chunk ((l&7) ^ (e&7)).
    const int esub   = lane >> 3;                 // == e&7
    const int bk_off = ((lane & 7) ^ esub) * 8;   // swizzled source element offset

    const int quad = lane >> 4;
    const int col  = lane & 15;

    f32x4 acc[2][2];
    #pragma unroll
    for (int mt = 0; mt < 2; ++mt)
        #pragma unroll
        for (int nt = 0; nt < 2; ++nt)
            acc[mt][nt] = f32x4{0.f, 0.f, 0.f, 0.f};

    // B-stage issuer: 4 DMA instrs/wave cover this wave's 32 experts, K-tile it.
    auto stage_b = [&](int it, int buf) {
        const int k0 = it * BK;
        #pragma unroll
        for (int jj = 0; jj < 4; ++jj) {
            const int e = wv * 32 + jj * 8 + esub;
            const unsigned short* gh = wh + (size_t)e * DIM + k0 + bk_off;
            unsigned short* dh = &lBh[buf][(wv * 32 + jj * 8) * BK]; // wave-uniform base
            __builtin_amdgcn_global_load_lds(
                (const __attribute__((address_space(1))) unsigned int*)gh,
                (__attribute__((address_space(3))) unsigned int*)dh, 16, 0, 0);
        }
    };

    // ---- prologue: A(0) store, B(0) DMA, x(1) prefetch.
    // Issue order matters for the counted vmcnt: queue = [B(0)x4, x(1)].
    float4 xv = *(const float4*)(xrow);          // x(0)
    stage_b(0, 0);
    {
        ushort4 h;
        h.x = f32_to_bf16(xv.x); h.y = f32_to_bf16(xv.y);
        h.z = f32_to_bf16(xv.z); h.w = f32_to_bf16(xv.w);
        *(ushort4*)&lAh[0][ta][kcol] = h;        // use drains x(0), B(0) stays
    }
    xv = *(const float4*)(xrow + BK);            // x(1)

    for (int it = 0; it < NITER; ++it) {
        const int cur = it & 1;
        const int nxt = cur ^ 1;

        if (it + 1 < NITER) {
            stage_b(it + 1, nxt);  // queue: B(it)x4, x(it+1), B(it+1)x4 = 9
            // retire exactly B(it) (leave x(it+1) + B(it+1)x4 in flight);
            // lgkmcnt(0) publishes our A(it) ds_writes from last iter.
            asm volatile("s_waitcnt vmcnt(5) lgkmcnt(0)" ::: "memory");
        } else {
            asm volatile("s_waitcnt vmcnt(0) lgkmcnt(0)" ::: "memory");
        }
        __builtin_amdgcn_s_barrier();            // A(it), B(it) ready everywhere
        asm volatile("" ::: "memory");

        // ---- stage A(it+1) into the other buffer; prefetch x(it+2).
        // Safe vs compute(it-1) readers of lAh[nxt]: they finished before the
        // trailing barrier of it-1.
        if (it + 1 < NITER) {
            ushort4 h;
            h.x = f32_to_bf16(xv.x); h.y = f32_to_bf16(xv.y);
            h.z = f32_to_bf16(xv.z); h.w = f32_to_bf16(xv.w);
            *(ushort4*)&lAh[nxt][ta][kcol] = h;  // use -> compiler vmcnt(4) on x(it+1)
            if (it + 2 < NITER)
                xv = *(const float4*)(xrow + (it + 2) * BK);
        }

        // ---- compute(it): 2 k-subtiles of 32; 4 MFMAs each
        #pragma unroll
        for (int kk = 0; kk < BK; kk += 32) {
            const int kc = kk >> 3;               // chunk base: 0 or 4
            bf16x8 ah[2], bh[2];
            #pragma unroll
            for (int mt = 0; mt < 2; ++mt)
                ah[mt] = *(const bf16x8*)&lAh[cur][mt * 16 + col][kk + quad * 8];
            #pragma unroll
            for (int nt = 0; nt < 2; ++nt) {
                const int e = wv * 32 + nt * 16 + col;
                const int cpos = (((kc + quad) ^ (col & 7)) * 8); // unswizzle (e&7==col&7)
                bh[nt] = *(const bf16x8*)&lBh[cur][e * BK + cpos];
            }
            #pragma unroll
            for (int mt = 0; mt < 2; ++mt)
                #pragma unroll
                for (int nt = 0; nt < 2; ++nt)
                    acc[mt][nt] = __builtin_amdgcn_mfma_f32_16x16x32_bf16(
                        ah[mt], bh[nt], acc[mt][nt], 0, 0, 0);
        }

        // ---- trailing barrier (drain-free): orders compute(it) before
        // B(it+2)/A(it+2) overwrite lXh[cur] at the top of iter it+1.
        asm volatile("" ::: "memory");
        __builtin_amdgcn_s_barrier();
        asm volatile("" ::: "memory");
    }

    // ---- epilogue: per-wave top-2 over its 32 experts, per token.
    // C/D layout (16x16): col = lane&15 (expert), row = quad*4 + reg (token).
    #pragma unroll
    for (int mt = 0; mt < 2; ++mt) {
        #pragma unroll
        for (int r = 0; r < 4; ++r) {
            float s0 = acc[mt][0][r]; int e0 = wv * 32 + col;
            float s1 = acc[mt][1][r]; int e1 = e0 + 16;
            float t1s, t2s; int t1e, t2e;
            if (s1 > s0) { t1s = s1; t1e = e1; t2s = s0; t2e = e0; }
            else         { t1s = s0; t1e = e0; t2s = s1; t2e = e1; }
            #pragma unroll
            for (int m = 1; m <= 8; m <<= 1) {
                float o1s = __shfl_xor(t1s, m); int o1e = __shfl_xor(t1e, m);
                float o2s = __shfl_xor(t2s, m); int o2e = __shfl_xor(t2e, m);
                bool o1_top = (o1s > t1s) || (o1s == t1s && o1e < t1e);
                if (o1_top) {
                    bool keep_t1 = (t1s > o2s) || (t1s == o2s && t1e < o2e);
                    t2s = keep_t1 ? t1s : o2s; t2e = keep_t1 ? t1e : o2e;
                    t1s = o1s; t1e = o1e;
                } else {
                    bool o1_2nd = (o1s > t2s) || (o1s == t2s && o1e < t2e);
                    if (o1_2nd) { t2s = o1s; t2e = o1e; }
                }
            }
            if (col == 0) {
                int tok = mt * 16 + quad * 4 + r;
                cand[wv][tok] = make_float4(t1s, __int_as_float(t1e), t2s, __int_as_float(t2e));
            }
        }
    }
    __syncthreads();

    // ---- final merge across waves; write outputs + near-tie flags
    if (tid < MB) {
        float4 c0 = cand[0][tid];
        float t1s = c0.x; int t1e = __float_as_int(c0.y);
        float t2s = c0.z; int t2e = __float_as_int(c0.w);
        #pragma unroll
        for (int wvi = 1; wvi < NWAVES; ++wvi) {
            float4 c = cand[wvi][tid];
            float o1s = c.x; int o1e = __float_as_int(c.y);
            float o2s = c.z; int o2e = __float_as_int(c.w);
            bool o1_top = (o1s > t1s) || (o1s == t1s && o1e < t1e);
            if (o1_top) {
                bool keep_t1 = (t1s > o2s) || (t1s == o2s && t1e < o2e);
                t2s = keep_t1 ? t1s : o2s; t2e = keep_t1 ? t1e : o2e;
                t1s = o1s; t1e = o1e;
            } else {
                bool o1_2nd = (o1s > t2s) || (o1s == t2s && o1e < t2e);
                if (o1_2nd) { t2s = o1s; t2e = o1e; }
            }
        }
        const int gtok = tok0 + tid;
        out[gtok] = 1.0f;                       // STE forward value at argmax
        out[NUM_TOKENS + gtok] = (float)t1e;    // index as float
        if (t1s - t2s < MARGIN) {
            int slot = atomicAdd(counter, 1);
            if (slot < CAP) entries[slot] = make_int4(gtok, t1e, t2e, 0);
        }
    }
}

// ---------------------------------------------------------------- kernel 3
// fp64 re-verification of near-tie tokens (one wave per flagged token).
__global__ void refine(const float* __restrict__ x,
                       const float* __restrict__ w,
                       const int* __restrict__ counter,
                       const int4* __restrict__ entries,
                       float* __restrict__ out) {
    const int gwave  = (blockIdx.x * blockDim.x + threadIdx.x) >> 6;
    const int lane   = threadIdx.x & 63;
    const int nwaves = (gridDim.x * blockDim.x) >> 6;
    int n = *counter; if (n > CAP) n = CAP;
    for (int i = gwave; i < n; i += nwaves) {
        int4 e = entries[i];
        const float* xr = x + (size_t)e.x * DIM;
        const float* w1 = w + (size_t)e.y * DIM;
        const float* w2 = w + (size_t)e.z * DIM;
        double d1 = 0.0, d2 = 0.0;
        for (int k = lane; k < DIM; k += 64) {
            double xv = (double)xr[k];
            d1 += xv * (double)w1[k];
            d2 += xv * (double)w2[k];
        }
        #pragma unroll
        for (int m = 32; m > 0; m >>= 1) {
            d1 += __shfl_xor(d1, m);
            d2 += __shfl_xor(d2, m);
        }
        if (lane == 0) {
            int best = (d1 > d2) ? e.y : ((d2 > d1) ? e.z : (e.y < e.z ? e.y : e.z));
            out[NUM_TOKENS + e.x] = (float)best;
        }
    }
}

// ---------------------------------------------------------------- launcher
extern "C" void kernel_launch(void* const* d_in, const int* in_sizes, int n_in,
                              void* d_out, int out_size, void* d_ws, size_t ws_size,
                              hipStream_t stream) {
    const float* x = (const float*)d_in[0];
    const float* w = (const float*)d_in[1];
    float* out = (float*)d_out;

    char* ws = (char*)d_ws;
    unsigned short* wh = (unsigned short*)ws;                     // 2 MB
    int*  counter = (int*)(ws + (2u << 20));
    int4* entries = (int4*)(ws + (2u << 20) + 16);                // 256 KB

    cvt_weights<<<256, 256, 0, stream>>>(w, wh, counter);
    gate_main<<<NUM_TOKENS / MB, 512, 0, stream>>>(x, wh, out, counter, entries);
    refine<<<256, 256, 0, stream>>>(x, w, counter, entries, out);
}